// Round 3
// baseline (210.009 us; speedup 1.0000x reference)
//
#include <hip/hip_runtime.h>

// SinusoidalSynthesizer: FLOAT32 inputs [8,250,100] x2 -> FLOAT32 outputs
//   chunk0: amplitude_envelopes [8,64000,100] f32 (51,200,000) at elem 0
//   chunk1: frequency_envelopes [8,250,100]   f32 (   200,000) at elem 51,200,000
//
// R8 = R7 resubmitted verbatim (R7 bench was an infra failure: "MI355X
// container failed twice" -- kernel never ran).
//
// R7 = R6 with the compile fix: __builtin_nontemporal_store requires a clang
// ext_vector_type, not HIP's float4 class. All 16B ops now use f32x4.
//
//  - Timed region includes the harness's 822 MB output re-poison fill
//    (~133 us at ~6.3 TB/s) -- untouchable. Our share was ~65-70 us at R5.
//  - R5 store loop: scalar dword stores + int-div + 3x ds_read_b32 per
//    4 bytes -> instruction-issue-bound at ~3.3 TB/s effective.
//  - New store loop: rows of 100 f32 are 25 aligned float4s (100 = 4*25),
//    so float4 fidx covers channels 4m..4m+3 of row q = fidx/25 with no
//    row-boundary crossing. 2x ds_read_b128 (Aprev, delta) + 4 fma +
//    1 nontemporal global_store_dwordx4 per 16 bytes.
//  - freq envelope fused into the which==0 setup threads (each (b,frame)
//    is visited exactly once by grid.x = 250); second launch removed.
//
// Math (unchanged, bitwise-identical amp path):
//   amp_env[b,t,c] = Ap[c] + w[r]*(Ag[c]-Ap[c]),  g = t/256+1, r = t%256
//   A = (2*sigmoid(amp)^ln10 + 1e-7) * ((f*(c+1) < 22050) + 1e-4)
//   f = 440*2^((sigmoid(frq)*119.2131 - 69)/12)

namespace {
constexpr int kB = 8;
constexpr int kF = 250;
constexpr int kC = 100;
constexpr int kHop = 256;
constexpr int kSamples = 64000;
constexpr size_t kAmpElems = (size_t)kB * kSamples * kC;  // 51,200,000
constexpr float kLog10 = 2.302585092994046f;
constexpr float kMidiMax = 119.213094853649121f;          // 12*(log2(8000)-log2(440))+69
constexpr float kPi = 3.14159265358979323846f;

typedef float f32x4 __attribute__((ext_vector_type(4)));

__device__ __forceinline__ float sigmoidf_(float x) {
    return 1.0f / (1.0f + expf(-x));
}
} // namespace

__global__ __launch_bounds__(256) void synth_kernel(
    const float* __restrict__ amp_in,
    const float* __restrict__ frq_in,
    float* __restrict__ amp_out,
    float* __restrict__ frq_out)
{
    const int gm1 = blockIdx.x;   // frame g-1 in [0,250); covers t in [gm1*256,(gm1+1)*256)
    const int b   = blockIdx.y;
    const int tid = threadIdx.x;

    __shared__ __align__(16) float sAp[kC];   // A[b, g-1, :]
    __shared__ __align__(16) float sD[kC];    // A[b, min(g,249), :] - A[b, g-1, :]
    __shared__ float sWin[kHop];

    // periodic hann 512, first half: w[r] = 0.5*(1 - cos(pi*r/256))
    sWin[tid] = 0.5f * (1.0f - cosf(kPi * (float)tid * (1.0f / 256.0f)));

    if (tid < 2 * kC) {
        const int which = (tid >= kC) ? 1 : 0;   // 0 -> frame g-1, 1 -> frame min(g,249)
        const int c = which ? (tid - kC) : tid;
        const int frame = which ? min(gm1 + 1, kF - 1) : gm1;
        const int idx = (b * kF + frame) * kC + c;
        const float xa = amp_in[idx];
        const float xf = frq_in[idx];
        const float a  = 2.0f * powf(sigmoidf_(xa), kLog10) + 1e-7f;
        const float f  = 440.0f * exp2f((sigmoidf_(xf) * kMidiMax - 69.0f) * (1.0f / 12.0f));
        const float aa = (f * (float)(c + 1) < 22050.0f) ? (1.0f + 1e-4f) : 1e-4f;
        const float A = a * aa;
        if (which) {
            sD[c] = A;                // temporarily holds A[g]; becomes delta below
        } else {
            sAp[c] = A;
            frq_out[idx] = f;         // fused freq envelope (each (b,frame) hit once)
        }
    }
    __syncthreads();
    if (tid < kC) sD[tid] -= sAp[tid];
    __syncthreads();

    // 6400 float4 stores per block: fidx in [0,6400), row q = fidx/25 (sample
    // within hop), m = fidx%25 -> channels 4m..4m+3. Consecutive lanes write
    // consecutive 16B -> fully coalesced 1 KiB per wave-instruction.
    const size_t base4 = (((size_t)b * kSamples + (size_t)gm1 * kHop) * (size_t)kC) / 4;
    f32x4* __restrict__ out4 = reinterpret_cast<f32x4*>(amp_out) + base4;
    const f32x4* ap4 = reinterpret_cast<const f32x4*>(sAp);
    const f32x4* d4  = reinterpret_cast<const f32x4*>(sD);

#pragma unroll
    for (int it = 0; it < 25; ++it) {
        const int fidx = tid + (it << 8);
        const int q = fidx / 25;          // magic-mul, no HW div
        const int m = fidx - q * 25;
        const float w = sWin[q];
        const f32x4 a = ap4[m];
        const f32x4 d = d4[m];
        f32x4 o;
        o.x = fmaf(w, d.x, a.x);
        o.y = fmaf(w, d.y, a.y);
        o.z = fmaf(w, d.z, a.z);
        o.w = fmaf(w, d.w, a.w);
        __builtin_nontemporal_store(o, out4 + fidx);   // write-once stream, skip L2
    }
}

extern "C" void kernel_launch(void* const* d_in, const int* in_sizes, int n_in,
                              void* d_out, int out_size, void* d_ws, size_t ws_size,
                              hipStream_t stream) {
    (void)in_sizes; (void)n_in; (void)out_size; (void)d_ws; (void)ws_size;
    const float* amp = (const float*)d_in[0];
    const float* frq = (const float*)d_in[1];
    float* out0 = (float*)d_out;           // amp env, f32 elems [0, 51.2M)
    float* out1 = out0 + kAmpElems;        // freq env, f32 elems [51.2M, 51.4M)

    dim3 grid(kF, kB);
    synth_kernel<<<grid, 256, 0, stream>>>(amp, frq, out0, out1);
}

// Round 4
// 200.918 us; speedup vs baseline: 1.0452x; 1.0452x over previous
//
#include <hip/hip_runtime.h>

// SinusoidalSynthesizer: FLOAT32 inputs [8,250,100] x2 -> FLOAT32 outputs
//   chunk0: amplitude_envelopes [8,64000,100] f32 (51,200,000) at elem 0
//   chunk1: frequency_envelopes [8,250,100]   f32 (   200,000) at elem 51,200,000
//
// R9 = R8 minus the nontemporal store hint. Single-variable experiment.
//
// R8 post-mortem: fused float4 kernel measured ~80 us (total 210 vs 202),
// WORSE than R5's scalar-store version (~65-70 us). LDS-conflict and VALU
// arithmetic both clear the ~100 cyc/KB HBM budget, so the instruction-mix
// theory was wrong. Prime suspect: __builtin_nontemporal_store's no-allocate
// L2 policy defeats TCC write-combining of 16B lane stores into full-line
// HBM bursts -> partial-line writes -> effective ~2.5 TB/s. Plain stores let
// L2 absorb and stream full lines.
//
// Math (unchanged, bitwise-identical amp path):
//   amp_env[b,t,c] = Ap[c] + w[r]*(Ag[c]-Ap[c]),  g = t/256+1, r = t%256
//   A = (2*sigmoid(amp)^ln10 + 1e-7) * ((f*(c+1) < 22050) + 1e-4)
//   f = 440*2^((sigmoid(frq)*119.2131 - 69)/12)
//
// Layout fact that makes float4 legal: 100 = 4*25, so a float4 at flat
// quad-index fidx covers channels 4m..4m+3 of sample-row q = fidx/25 and
// never crosses a row boundary.

namespace {
constexpr int kB = 8;
constexpr int kF = 250;
constexpr int kC = 100;
constexpr int kHop = 256;
constexpr int kSamples = 64000;
constexpr size_t kAmpElems = (size_t)kB * kSamples * kC;  // 51,200,000
constexpr float kLog10 = 2.302585092994046f;
constexpr float kMidiMax = 119.213094853649121f;          // 12*(log2(8000)-log2(440))+69
constexpr float kPi = 3.14159265358979323846f;

typedef float f32x4 __attribute__((ext_vector_type(4)));

__device__ __forceinline__ float sigmoidf_(float x) {
    return 1.0f / (1.0f + expf(-x));
}
} // namespace

__global__ __launch_bounds__(256) void synth_kernel(
    const float* __restrict__ amp_in,
    const float* __restrict__ frq_in,
    float* __restrict__ amp_out,
    float* __restrict__ frq_out)
{
    const int gm1 = blockIdx.x;   // frame g-1 in [0,250); covers t in [gm1*256,(gm1+1)*256)
    const int b   = blockIdx.y;
    const int tid = threadIdx.x;

    __shared__ __align__(16) float sAp[kC];   // A[b, g-1, :]
    __shared__ __align__(16) float sD[kC];    // A[b, min(g,249), :] - A[b, g-1, :]
    __shared__ float sWin[kHop];

    // periodic hann 512, first half: w[r] = 0.5*(1 - cos(pi*r/256))
    sWin[tid] = 0.5f * (1.0f - cosf(kPi * (float)tid * (1.0f / 256.0f)));

    if (tid < 2 * kC) {
        const int which = (tid >= kC) ? 1 : 0;   // 0 -> frame g-1, 1 -> frame min(g,249)
        const int c = which ? (tid - kC) : tid;
        const int frame = which ? min(gm1 + 1, kF - 1) : gm1;
        const int idx = (b * kF + frame) * kC + c;
        const float xa = amp_in[idx];
        const float xf = frq_in[idx];
        const float a  = 2.0f * powf(sigmoidf_(xa), kLog10) + 1e-7f;
        const float f  = 440.0f * exp2f((sigmoidf_(xf) * kMidiMax - 69.0f) * (1.0f / 12.0f));
        const float aa = (f * (float)(c + 1) < 22050.0f) ? (1.0f + 1e-4f) : 1e-4f;
        const float A = a * aa;
        if (which) {
            sD[c] = A;                // temporarily holds A[g]; becomes delta below
        } else {
            sAp[c] = A;
            frq_out[idx] = f;         // fused freq envelope (each (b,frame) hit once)
        }
    }
    __syncthreads();
    if (tid < kC) sD[tid] -= sAp[tid];
    __syncthreads();

    // 6400 float4 stores per block: fidx in [0,6400), row q = fidx/25 (sample
    // within hop), m = fidx%25 -> channels 4m..4m+3. Consecutive lanes write
    // consecutive 16B -> fully coalesced 1 KiB per wave-instruction.
    const size_t base4 = (((size_t)b * kSamples + (size_t)gm1 * kHop) * (size_t)kC) / 4;
    f32x4* __restrict__ out4 = reinterpret_cast<f32x4*>(amp_out) + base4;
    const f32x4* ap4 = reinterpret_cast<const f32x4*>(sAp);
    const f32x4* d4  = reinterpret_cast<const f32x4*>(sD);

#pragma unroll
    for (int it = 0; it < 25; ++it) {
        const int fidx = tid + (it << 8);
        const int q = fidx / 25;          // magic-mul, no HW div
        const int m = fidx - q * 25;
        const float w = sWin[q];
        const f32x4 a = ap4[m];
        const f32x4 d = d4[m];
        f32x4 o;
        o.x = fmaf(w, d.x, a.x);
        o.y = fmaf(w, d.y, a.y);
        o.z = fmaf(w, d.z, a.z);
        o.w = fmaf(w, d.w, a.w);
        out4[fidx] = o;                   // plain store: let L2 write-combine
    }
}

extern "C" void kernel_launch(void* const* d_in, const int* in_sizes, int n_in,
                              void* d_out, int out_size, void* d_ws, size_t ws_size,
                              hipStream_t stream) {
    (void)in_sizes; (void)n_in; (void)out_size; (void)d_ws; (void)ws_size;
    const float* amp = (const float*)d_in[0];
    const float* frq = (const float*)d_in[1];
    float* out0 = (float*)d_out;           // amp env, f32 elems [0, 51.2M)
    float* out1 = out0 + kAmpElems;        // freq env, f32 elems [51.2M, 51.4M)

    dim3 grid(kF, kB);
    synth_kernel<<<grid, 256, 0, stream>>>(amp, frq, out0, out1);
}